// Round 3
// baseline (391.723 us; speedup 1.0000x reference)
//
#include <hip/hip_runtime.h>
#include <cstdint>

#define M_DIM 8192   // B*S = 4*2048
#define N_DIM 4096   // D_OUT
#define K_DIM 4096   // D_IN
#define NT    32     // K_DIM / 128 K-tiles

typedef int i32x4 __attribute__((ext_vector_type(4)));

// async global->LDS, 16B per lane. LDS dest is wave-uniform base; HW
// scatters lane i to base + i*16. Global source IS per-lane (swizzle there).
__device__ __forceinline__ void gload_lds16(const void* g, void* l) {
  __builtin_amdgcn_global_load_lds(
      (const __attribute__((address_space(1))) unsigned int*)(uintptr_t)g,
      (__attribute__((address_space(3))) unsigned int*)(uintptr_t)l,
      16, 0, 0);
}

// ---------------- prep (unchanged) ----------------
__global__ __launch_bounds__(256) void prep_kernel(
    const float* __restrict__ x, const int* __restrict__ q,
    signed char* __restrict__ xq, signed char* __restrict__ wq8,
    float* __restrict__ sx, float* __restrict__ si) {
  const int tid  = threadIdx.x;
  const int lane = tid & 63;
  const int wv   = tid >> 6;
  if (blockIdx.x < 2048) {
    const int row = blockIdx.x * 4 + wv;
    const float* xr = x + (size_t)row * K_DIM;
    signed char* xo = xq + (size_t)row * K_DIM;
    float4 v[16];
    float amax = 0.f;
#pragma unroll
    for (int j = 0; j < 16; ++j) {
      v[j] = *(const float4*)(xr + j * 256 + lane * 4);
      amax = fmaxf(amax, fmaxf(fmaxf(fabsf(v[j].x), fabsf(v[j].y)),
                               fmaxf(fabsf(v[j].z), fabsf(v[j].w))));
    }
#pragma unroll
    for (int off = 32; off > 0; off >>= 1)
      amax = fmaxf(amax, __shfl_xor(amax, off, 64));
    const float inv = amax > 0.f ? 127.f / amax : 0.f;
    int isum = 0;
#pragma unroll
    for (int j = 0; j < 16; ++j) {
      int ix = __float2int_rn(v[j].x * inv);
      int iy = __float2int_rn(v[j].y * inv);
      int iz = __float2int_rn(v[j].z * inv);
      int iw = __float2int_rn(v[j].w * inv);
      isum += ix + iy + iz + iw;
      char4 o; o.x = (char)ix; o.y = (char)iy; o.z = (char)iz; o.w = (char)iw;
      *(char4*)(xo + j * 256 + lane * 4) = o;
    }
#pragma unroll
    for (int off = 32; off > 0; off >>= 1)
      isum += __shfl_xor(isum, off, 64);
    if (lane == 0) {
      sx[row] = amax * (1.f / 127.f);
      si[row] = (float)isum;
    }
  } else {
    const int bid = blockIdx.x - 2048;               // 0..1023
    const size_t total  = (size_t)N_DIM * K_DIM;     // 16.78M ints
    const size_t stride = (size_t)1024 * 4096;       // ints per sweep
    for (size_t base = (size_t)bid * 4096; base < total; base += stride) {
#pragma unroll
      for (int u = 0; u < 4; ++u) {
        const size_t idx = base + (size_t)u * 1024 + tid * 4;
        int4 w = *(const int4*)(q + idx);
        char4 o; o.x = (char)w.x; o.y = (char)w.y; o.z = (char)w.z; o.w = (char)w.w;
        *(char4*)(wq8 + idx) = o;
      }
    }
  }
}

// ---------------- GEMM i8, 256x256 tile, BK=128, 8 waves ------------------
// ONE barrier + ONE vmcnt(0) per K-tile; stages issued at tile START (a
// single sched fence pins them there), tile body (24 ds_read_b128 + 64 MFMA)
// is barrier-free so the compiler schedules the whole window with its own
// fine-grained lgkmcnt interleave (m97 lesson; round-2's manual pinning
// regressed).
//
// Correctness ledger:
//  - entry invariant at tile t: LDS[buf] holds tile t, collectivized by the
//    barrier at end of tile t-1; LDS[buf^1] (tile t-1) is dead, because every
//    wave's tile-t-1 ds_reads were consumed by its MFMAs before that barrier.
//  - stages into buf^1 are issued only after that barrier -> no overwrite race.
//  - end of tile t: per-wave vmcnt(0) (its 8 stage-loads for t+1 landed;
//    issued ~2600 cyc earlier so this is cheap) then s_barrier collectivizes.
__global__ __launch_bounds__(512, 2) void qlinear_gemm_kernel(
    const signed char* __restrict__ A,     // [M][K] int8
    const signed char* __restrict__ Bm,    // [N][K] int8
    const float* __restrict__ sx,          // [M]
    const float* __restrict__ si,          // [M]
    const float* __restrict__ scale_p, const float* __restrict__ zp_p,
    const float* __restrict__ bias,        // [N]
    float* __restrict__ out) {             // [M][N] fp32
  __shared__ signed char sA[2][2][16384];  // 64 KB
  __shared__ signed char sB[2][2][16384];  // 64 KB

  const int tid  = threadIdx.x;
  const int lane = tid & 63;
  const int w    = tid >> 6;     // wave 0..7
  const int wr   = w >> 2;       // 0..1 : wave row (M), owns A-half wr
  const int wc   = w & 3;        // 0..3 : wave col (N)
  const int lr   = lane & 15;
  const int quad = lane >> 4;

  // XCD-chunked swizzle (bijective: 512 % 8 == 0)
  const int bid = blockIdx.x;                  // 0..511
  const int swz = (bid & 7) * 64 + (bid >> 3);
  const int bm  = (swz >> 4) * 256;            // 32 M-rows
  const int bn  = (swz & 15) * 256;            // 16 N-cols

  // ---- staging: per-lane pre-swizzled global source ----
  const int srow = lane >> 3;              // row within 8-row wave slab
  const int cg   = (lane & 7) ^ srow;      // global 16B chunk for this lane
  const signed char* aG = A  + (size_t)(bm + w * 8 + srow) * K_DIM + cg * 16;
  const signed char* bG = Bm + (size_t)(bn + w * 8 + srow) * K_DIM + cg * 16;
  const int dwoff = w * 1024;              // wave-uniform LDS slab offset

#define STG_A(dst, h, c, t) \
  gload_lds16(aG + (size_t)((h) * 128 + (c) * 64) * K_DIM + (size_t)(t) * 128, \
              (dst) + (h) * 16384 + (c) * 8192 + dwoff)
#define STG_B(dst, h, c, t) \
  gload_lds16(bG + (size_t)((h) * 128 + (c) * 64) * K_DIM + (size_t)(t) * 128, \
              (dst) + (h) * 16384 + (c) * 8192 + dwoff)

  // read-side swizzled byte offsets per k-substep
  int off[2];
#pragma unroll
  for (int ks = 0; ks < 2; ++ks)
    off[ks] = lr * 128 + (((ks * 4 + quad) ^ (lr & 7)) * 16);

  i32x4 acc[8][4] = {};

  // ---- prologue: stage tile 0, drain, collectivize ----
  {
    signed char* dA = &sA[0][0][0];
    signed char* dB = &sB[0][0][0];
    STG_B(dB, 0, 0, 0); STG_B(dB, 0, 1, 0);
    STG_B(dB, 1, 0, 0); STG_B(dB, 1, 1, 0);
    STG_A(dA, 0, 0, 0); STG_A(dA, 1, 0, 0);
    STG_A(dA, 0, 1, 0); STG_A(dA, 1, 1, 0);
  }
  asm volatile("s_waitcnt vmcnt(0)" ::: "memory");
  __builtin_amdgcn_s_barrier();

  for (int t = 0; t < NT; ++t) {
    const int buf = t & 1;
    const signed char* pA = &sA[buf][wr][0];
    const signed char* pB = &sB[buf][wc >> 1][0] + (wc & 1) * 8192;
    signed char* nA = &sA[buf ^ 1][0][0];
    signed char* nB = &sB[buf ^ 1][0][0];
    const bool st = (t + 1) < NT;
    const int tn = t + 1;

    // ---- stage tile t+1 into the dead buffer, pinned to tile start ----
    if (st) {
      STG_B(nB, 0, 0, tn); STG_B(nB, 0, 1, tn);
      STG_B(nB, 1, 0, tn); STG_B(nB, 1, 1, tn);
      STG_A(nA, 0, 0, tn); STG_A(nA, 1, 0, tn);
      STG_A(nA, 0, 1, tn); STG_A(nA, 1, 1, tn);
    }
    __builtin_amdgcn_sched_barrier(0);  // keep stages at tile start (only fence)

    // ---- barrier-free tile body: compiler schedules reads vs MFMA ----
    i32x4 bfr[4][2], afr[4][2];
#pragma unroll
    for (int n = 0; n < 4; ++n)
#pragma unroll
      for (int ks = 0; ks < 2; ++ks)
        bfr[n][ks] = *(const i32x4*)(pB + n * 2048 + off[ks]);
#pragma unroll
    for (int m = 0; m < 4; ++m)
#pragma unroll
      for (int ks = 0; ks < 2; ++ks)
        afr[m][ks] = *(const i32x4*)(pA + m * 2048 + off[ks]);

#pragma unroll
    for (int m = 0; m < 4; ++m)
#pragma unroll
      for (int n = 0; n < 4; ++n)
#pragma unroll
        for (int ks = 0; ks < 2; ++ks)
          acc[m][n] = __builtin_amdgcn_mfma_i32_16x16x64_i8(
              afr[m][ks], bfr[n][ks], acc[m][n], 0, 0, 0);

    i32x4 afr2[4][2];
#pragma unroll
    for (int m = 0; m < 4; ++m)
#pragma unroll
      for (int ks = 0; ks < 2; ++ks)
        afr2[m][ks] = *(const i32x4*)(pA + 8192 + m * 2048 + off[ks]);

#pragma unroll
    for (int m = 0; m < 4; ++m)
#pragma unroll
      for (int n = 0; n < 4; ++n)
#pragma unroll
        for (int ks = 0; ks < 2; ++ks)
          acc[4 + m][n] = __builtin_amdgcn_mfma_i32_16x16x64_i8(
              afr2[m][ks], bfr[n][ks], acc[4 + m][n], 0, 0, 0);

    // ---- tile end: collectivize tile t+1, retire buf^1 ----
    if (st) {
      asm volatile("s_waitcnt vmcnt(0)" ::: "memory");
      __builtin_amdgcn_s_barrier();
    }
  }
#undef STG_A
#undef STG_B

  // ---------- epilogue ----------
  const float scale = *scale_p;
  const float zp    = *zp_p;
  // C/D layout: col = lane&15, row = quad*4 + reg (dtype-independent)
#pragma unroll
  for (int i = 0; i < 8; ++i) {
    const int gm0 = bm + wr * 128 + i * 16 + quad * 4;
    float am[4], cm[4];
#pragma unroll
    for (int r = 0; r < 4; ++r) {
      am[r] = scale * sx[gm0 + r];
      cm[r] = -am[r] * zp * si[gm0 + r];
    }
#pragma unroll
    for (int j = 0; j < 4; ++j) {
      const int gn = bn + wc * 64 + j * 16 + lr;
      const float bb = bias[gn];
#pragma unroll
      for (int r = 0; r < 4; ++r)
        out[(size_t)(gm0 + r) * N_DIM + gn] =
            am[r] * (float)acc[i][j][r] + cm[r] + bb;
    }
  }
}

extern "C" void kernel_launch(void* const* d_in, const int* in_sizes, int n_in,
                              void* d_out, int out_size, void* d_ws, size_t ws_size,
                              hipStream_t stream) {
  const float* x     = (const float*)d_in[0];
  const int*   wq    = (const int*)d_in[1];
  const float* scale = (const float*)d_in[2];
  const float* zp    = (const float*)d_in[3];
  const float* bias  = (const float*)d_in[4];
  float* out = (float*)d_out;

  // ws: xq (8192*4096 i8) | wq8 (4096*4096 i8) | sx | si
  signed char* xq  = (signed char*)d_ws;
  signed char* wq8 = xq + (size_t)M_DIM * K_DIM;
  float* sx = (float*)(wq8 + (size_t)N_DIM * K_DIM);
  float* si = sx + M_DIM;

  prep_kernel<<<3072, 256, 0, stream>>>(x, wq, xq, wq8, sx, si);
  qlinear_gemm_kernel<<<512, 512, 0, stream>>>(xq, wq8, sx, si, scale, zp, bias, out);
}